// Round 1
// baseline (168.946 us; speedup 1.0000x reference)
//
#include <hip/hip_runtime.h>
#include <hip/hip_bf16.h>

// AdaCoF frame interpolation, fully fused:
//   out[b,c,i,j] = sum_t occ_softmax[b,t,i,j] *
//                  sum_k softmax_k(weights)[b,t,k,i,j] *
//                        bilerp(frame_pad[t,b,c], i + k/5 + alpha, j + k%5 + beta)
// Dims fixed by the reference: T=2, B=4, C=3, H=W=256, KS=5 (K2=25), PAD=2.

#define KS 5
#define K2 25
#define PADR 2

constexpr int T_ = 2;
constexpr int B_ = 4;
constexpr int C_ = 3;
constexpr int H_ = 256;
constexpr int W_ = 256;
constexpr int HW_ = H_ * W_;
constexpr float HP_MAX = (float)(H_ + 2 * PADR - 1);  // 259
constexpr float WP_MAX = (float)(W_ + 2 * PADR - 1);  // 259
constexpr float HP_M2 = (float)(H_ + 2 * PADR - 2);   // 258
constexpr float WP_M2 = (float)(W_ + 2 * PADR - 2);   // 258

__global__ __launch_bounds__(256) void adacof_fused(
    const float* __restrict__ frames,   // [T,B,C,H,W]
    const float* __restrict__ weights,  // [B,T,K2,H,W]
    const float* __restrict__ alphas,   // [B,T,K2,H,W]
    const float* __restrict__ betas,    // [B,T,K2,H,W]
    const float* __restrict__ occl,     // [B,T,H,W]
    float* __restrict__ out)            // [B,C,H,W]
{
    const int idx = blockIdx.x * blockDim.x + threadIdx.x;
    if (idx >= B_ * HW_) return;
    const int b  = idx / HW_;
    const int ij = idx - b * HW_;
    const int i  = ij >> 8;        // / W_
    const int j  = ij & (W_ - 1);  // % W_

    // ---- occlusion softmax over T=2 ----
    const float o0 = occl[(b * T_ + 0) * HW_ + ij];
    const float o1 = occl[(b * T_ + 1) * HW_ + ij];
    const float om = fmaxf(o0, o1);
    const float e0 = __expf(o0 - om);
    const float e1 = __expf(o1 - om);
    const float oinv = 1.0f / (e0 + e1);
    float occw[T_] = {e0 * oinv, e1 * oinv};

    float acc0 = 0.0f, acc1 = 0.0f, acc2 = 0.0f;

    #pragma unroll
    for (int t = 0; t < T_; ++t) {
        const int bt = (b * T_ + t) * K2 * HW_ + ij;
        const float* __restrict__ wp = weights + bt;
        const float* __restrict__ ap = alphas + bt;
        const float* __restrict__ bp = betas + bt;
        const float* __restrict__ fb = frames + (size_t)(t * B_ + b) * C_ * HW_;

        // ---- weight softmax over K2=25, kept in registers ----
        float wk[K2];
        float wmax = -3.0e38f;
        #pragma unroll
        for (int k = 0; k < K2; ++k) {
            wk[k] = wp[k * HW_];
            wmax = fmaxf(wmax, wk[k]);
        }
        float wsum = 0.0f;
        #pragma unroll
        for (int k = 0; k < K2; ++k) {
            wk[k] = __expf(wk[k] - wmax);
            wsum += wk[k];
        }
        const float wscale = occw[t] / wsum;   // fold occlusion weight in

        #pragma unroll
        for (int k = 0; k < K2; ++k) {
            const float a  = ap[k * HW_];
            const float bb = bp[k * HW_];
            const float dy = (float)(k / KS);
            const float dx = (float)(k % KS);

            // padded-space coordinates, clipped per reference
            float y = fminf(fmaxf(a + dy + (float)i, 0.0f), HP_MAX);
            float x = fminf(fmaxf(bb + dx + (float)j, 0.0f), WP_MAX);
            float y0f = fminf(floorf(y), HP_M2);   // clip(floor(y),0,Hp-2); >=0 already
            float x0f = fminf(floorf(x), WP_M2);
            const float fy = y - y0f;
            const float fx = x - x0f;
            const int y0 = (int)y0f;
            const int x0 = (int)x0f;

            // edge-replication pad folded into index clamps (fp[y] = frame[clamp(y-2,0,255)])
            const int iy0 = min(max(y0 - PADR, 0), H_ - 1);
            const int iy1 = min(max(y0 + 1 - PADR, 0), H_ - 1);
            const int ix0 = min(max(x0 - PADR, 0), W_ - 1);
            const int ix1 = min(max(x0 + 1 - PADR, 0), W_ - 1);

            const float wgt = wk[k] * wscale;
            const float c00 = (1.0f - fy) * (1.0f - fx) * wgt;
            const float c01 = (1.0f - fy) * fx * wgt;
            const float c10 = fy * (1.0f - fx) * wgt;
            const float c11 = fy * fx * wgt;

            const int r0 = iy0 * W_;
            const int r1 = iy1 * W_;

            {   // c = 0
                const float* __restrict__ fp = fb;
                acc0 += c00 * fp[r0 + ix0] + c01 * fp[r0 + ix1]
                      + c10 * fp[r1 + ix0] + c11 * fp[r1 + ix1];
            }
            {   // c = 1
                const float* __restrict__ fp = fb + HW_;
                acc1 += c00 * fp[r0 + ix0] + c01 * fp[r0 + ix1]
                      + c10 * fp[r1 + ix0] + c11 * fp[r1 + ix1];
            }
            {   // c = 2
                const float* __restrict__ fp = fb + 2 * HW_;
                acc2 += c00 * fp[r0 + ix0] + c01 * fp[r0 + ix1]
                      + c10 * fp[r1 + ix0] + c11 * fp[r1 + ix1];
            }
        }
    }

    out[(b * C_ + 0) * HW_ + ij] = acc0;
    out[(b * C_ + 1) * HW_ + ij] = acc1;
    out[(b * C_ + 2) * HW_ + ij] = acc2;
}

extern "C" void kernel_launch(void* const* d_in, const int* in_sizes, int n_in,
                              void* d_out, int out_size, void* d_ws, size_t ws_size,
                              hipStream_t stream) {
    const float* frames  = (const float*)d_in[0];
    const float* weights = (const float*)d_in[1];
    const float* alphas  = (const float*)d_in[2];
    const float* betas   = (const float*)d_in[3];
    const float* occl    = (const float*)d_in[4];
    float* out = (float*)d_out;

    const int total = B_ * HW_;              // 262144 threads
    const int block = 256;
    const int grid = (total + block - 1) / block;
    adacof_fused<<<grid, block, 0, stream>>>(frames, weights, alphas, betas, occl, out);
}